// Round 2
// baseline (2075.666 us; speedup 1.0000x reference)
//
#include <hip/hip_runtime.h>

// CANPathIntegrator — MI355X round 2 (dtype-adaptive correctness)
// B=512, T=128, D=512, K=256. Grid: 256 blocks x 512 threads; block g owns
// batches 2g, 2g+1 (zero cross-block comms).
// dx_can = ALPHA * sum_k (w[2k+1]*zx[2k] - w[2k]*zx[2k+1]) * omega_k,
//   w = A zx, zx = T(omega@x) z0_base/(||z0_base||+eps).  A symmetric ->
// read column-coalesced A[j][i]. All compute f32.
// Input dtype sniffed at runtime via bitwise symmetry of A under the f32
// interpretation (u32[j] == u32[j*512] holds only if data really is f32).
// Output dtype mirrors input dtype.

namespace {
constexpr int NB = 512;
constexpr int NT = 128;
constexpr int ND = 512;
constexpr int NK = 256;
}

__device__ __forceinline__ float bf_to_f(unsigned short s) {
    return __uint_as_float((unsigned int)s << 16);
}
__device__ __forceinline__ float2 bf2_to_f2(unsigned int u) {
    return make_float2(__uint_as_float(u << 16),
                       __uint_as_float(u & 0xffff0000u));
}
__device__ __forceinline__ unsigned int f2_to_bf2(float a, float b) {
    unsigned int ua = __float_as_uint(a);
    unsigned int ub = __float_as_uint(b);
    ua += 0x7fffu + ((ua >> 16) & 1u);   // RNE
    ub += 0x7fffu + ((ub >> 16) & 1u);
    return (ua >> 16) | (ub & 0xffff0000u);
}

template <bool F32>
__device__ __forceinline__ float2 ld2(const void* p, size_t pairIdx) {
    if constexpr (F32)
        return reinterpret_cast<const float2*>(p)[pairIdx];
    else
        return bf2_to_f2(reinterpret_cast<const unsigned int*>(p)[pairIdx]);
}
template <bool F32>
__device__ __forceinline__ float ld1(const void* p, size_t i) {
    if constexpr (F32)
        return reinterpret_cast<const float*>(p)[i];
    else
        return bf_to_f(reinterpret_cast<const unsigned short*>(p)[i]);
}
template <bool F32>
__device__ __forceinline__ void st2(void* p, size_t pairIdx, float a, float b) {
    if constexpr (F32)
        reinterpret_cast<float2*>(p)[pairIdx] = make_float2(a, b);
    else
        reinterpret_cast<unsigned int*>(p)[pairIdx] = f2_to_bf2(a, b);
}

struct Shm {
    float zx[ND][2];      // interleaved (batch a, batch b)
    float wpart[NK][4];   // h=1 matvec partials
    float red[8][4];      // cross-wave reduction
    float dpi[2][NT][2];  // preloaded dx_pi for both batches
};

template <bool F32>
__device__ void run_can(Shm& sh,
                        const void* __restrict__ dx_pi,
                        const void* __restrict__ z0,
                        const void* __restrict__ x0,
                        const void* __restrict__ omega,
                        const void* __restrict__ A,
                        const void* __restrict__ z0b,
                        void* __restrict__ d_out)
{
    void* z_seq = d_out;
    void* x_seq = (char*)d_out + (size_t)NB * NT * ND * (F32 ? 4 : 2);

    const int tid = threadIdx.x;
    const int b0  = 2 * blockIdx.x;
    const int h   = tid >> 8;        // row half of A
    const int p   = tid & 255;       // column pair (cols 2p, 2p+1)

    // ---- preload dx_pi for this block's two batches into LDS (f32) ----
    if (tid < 2 * NT) {
        int bb = tid >> 7, tt = tid & 127;
        float2 v = ld2<F32>(dx_pi, (size_t)(b0 + bb) * NT + tt);
        sh.dpi[bb][tt][0] = v.x;
        sh.dpi[bb][tt][1] = v.y;
    }

    // ---- ||z0_base|| (block reduction) ----
    float sq;
    {
        float f = ld1<F32>(z0b, tid);
        sq = f * f;
    }
    #pragma unroll
    for (int off = 1; off < 64; off <<= 1) sq += __shfl_xor(sq, off, 64);
    if ((tid & 63) == 0) sh.red[tid >> 6][0] = sq;
    __syncthreads();
    float nsq = 0.f;
    #pragma unroll
    for (int w = 0; w < 8; ++w) nsq += sh.red[w][0];
    const float zinv = 1.0f / (sqrtf(nsq) + 1e-5f);
    __syncthreads();

    // ---- pair-owner persistent state (tid < 256, pair k = p) ----
    float om0 = 0.f, om1 = 0.f, v0 = 0.f, v1 = 0.f;
    float za0 = 0.f, za1 = 0.f, zb0 = 0.f, zb1 = 0.f;
    float xa0 = 0.f, xa1 = 0.f, xb0 = 0.f, xb1 = 0.f;
    if (h == 0) {
        float2 om = ld2<F32>(omega, p);
        om0 = om.x; om1 = om.y;
        float2 vv = ld2<F32>(z0b, p);
        v0 = vv.x * zinv; v1 = vv.y * zinv;
        float2 za = ld2<F32>(z0, (size_t)b0 * (ND / 2) + p);
        za0 = za.x; za1 = za.y;
        float2 zb = ld2<F32>(z0, (size_t)(b0 + 1) * (ND / 2) + p);
        zb0 = zb.x; zb1 = zb.y;
        float2 xa = ld2<F32>(x0, b0);
        xa0 = xa.x; xa1 = xa.y;
        float2 xb = ld2<F32>(x0, b0 + 1);
        xb0 = xb.x; xb1 = xb.y;
    }

    for (int t = 0; t < NT; ++t) {
        // (1) zx = T(omega@x) z0hat  -> LDS
        if (h == 0) {
            float tha = om0 * xa0 + om1 * xa1;
            float thb = om0 * xb0 + om1 * xb1;
            float ca, sa, cb, sb;
            __sincosf(tha, &sa, &ca);
            __sincosf(thb, &sb, &cb);
            sh.zx[2 * p][0]     = ca * v0 - sa * v1;
            sh.zx[2 * p + 1][0] = sa * v0 + ca * v1;
            sh.zx[2 * p][1]     = cb * v0 - sb * v1;
            sh.zx[2 * p + 1][1] = sb * v0 + cb * v1;
        }
        __syncthreads();

        // (2) half-matvec: w[2p],w[2p+1] partial over rows [h*256, h*256+256)
        float acc0a = 0.f, acc1a = 0.f, acc0b = 0.f, acc1b = 0.f;
        {
            const float(*__restrict__ zh)[2] = &sh.zx[h * 256];
            const size_t rowbase = (size_t)(h * 256) * (ND / 2) + p;
            #pragma unroll 8
            for (int j = 0; j < 256; ++j) {
                float2 av = ld2<F32>(A, rowbase + (size_t)j * (ND / 2));
                float zja = zh[j][0];
                float zjb = zh[j][1];
                acc0a = fmaf(av.x, zja, acc0a);
                acc1a = fmaf(av.y, zja, acc1a);
                acc0b = fmaf(av.x, zjb, acc0b);
                acc1b = fmaf(av.y, zjb, acc1b);
            }
        }
        if (h == 1) {
            sh.wpart[p][0] = acc0a; sh.wpart[p][1] = acc1a;
            sh.wpart[p][2] = acc0b; sh.wpart[p][3] = acc1b;
        }
        __syncthreads();

        // (3) g_k and dx_can partials (pair owners), then block reduction
        float d0a = 0.f, d1a = 0.f, d0b = 0.f, d1b = 0.f;
        if (h == 0) {
            float w0a = acc0a + sh.wpart[p][0];
            float w1a = acc1a + sh.wpart[p][1];
            float w0b = acc0b + sh.wpart[p][2];
            float w1b = acc1b + sh.wpart[p][3];
            float ga = w1a * sh.zx[2 * p][0] - w0a * sh.zx[2 * p + 1][0];
            float gb = w1b * sh.zx[2 * p][1] - w0b * sh.zx[2 * p + 1][1];
            d0a = ga * om0; d1a = ga * om1;
            d0b = gb * om0; d1b = gb * om1;
        }
        #pragma unroll
        for (int off = 1; off < 64; off <<= 1) {
            d0a += __shfl_xor(d0a, off, 64);
            d1a += __shfl_xor(d1a, off, 64);
            d0b += __shfl_xor(d0b, off, 64);
            d1b += __shfl_xor(d1b, off, 64);
        }
        if ((tid & 63) == 0) {
            int w = tid >> 6;
            sh.red[w][0] = d0a; sh.red[w][1] = d1a;
            sh.red[w][2] = d0b; sh.red[w][3] = d1b;
        }
        __syncthreads();

        // (4) finalize dx_total, rotate carry z, write outputs, update x
        if (h == 0) {
            float s0a = 0.f, s1a = 0.f, s0b = 0.f, s1b = 0.f;
            #pragma unroll
            for (int w = 0; w < 8; ++w) {
                s0a += sh.red[w][0]; s1a += sh.red[w][1];
                s0b += sh.red[w][2]; s1b += sh.red[w][3];
            }
            float dta0 = sh.dpi[0][t][0] + 0.1f * s0a;
            float dta1 = sh.dpi[0][t][1] + 0.1f * s1a;
            float dtb0 = sh.dpi[1][t][0] + 0.1f * s0b;
            float dtb1 = sh.dpi[1][t][1] + 0.1f * s1b;

            float tha = om0 * dta0 + om1 * dta1;
            float thb = om0 * dtb0 + om1 * dtb1;
            float ca, sa, cb, sb;
            __sincosf(tha, &sa, &ca);
            __sincosf(thb, &sb, &cb);
            float na0 = ca * za0 - sa * za1;
            float na1 = sa * za0 + ca * za1;
            float nb0 = cb * zb0 - sb * zb1;
            float nb1 = sb * zb0 + cb * zb1;
            za0 = na0; za1 = na1; zb0 = nb0; zb1 = nb1;

            st2<F32>(z_seq, ((size_t)b0 * NT + t) * (ND / 2) + p, na0, na1);
            st2<F32>(z_seq, ((size_t)(b0 + 1) * NT + t) * (ND / 2) + p, nb0, nb1);

            xa0 = fminf(fmaxf(xa0 + dta0, 0.f), 2.0f);
            xa1 = fminf(fmaxf(xa1 + dta1, 0.f), 2.0f);
            xb0 = fminf(fmaxf(xb0 + dtb0, 0.f), 2.0f);
            xb1 = fminf(fmaxf(xb1 + dtb1, 0.f), 2.0f);
            if (p == 0) {
                st2<F32>(x_seq, (size_t)b0 * NT + t, xa0, xa1);
                st2<F32>(x_seq, (size_t)(b0 + 1) * NT + t, xb0, xb1);
            }
        }
        __syncthreads();
    }
}

__global__ __launch_bounds__(512) void can_kernel(
    const void* __restrict__ dx_pi,
    const void* __restrict__ z0,
    const void* __restrict__ x0,
    const void* __restrict__ omega,
    const void* __restrict__ A,
    const void* __restrict__ z0b,
    void* __restrict__ d_out)
{
    __shared__ Shm sh;

    // ---- dtype sniff: bitwise symmetry of A under the f32 interpretation.
    // If A really is f32 [512][512], u32[j] == u32[j*512] exactly (A was
    // built as 0.5*(A+A^T) in f32). If A is bf16, u32[j] packs
    // (A[0][2j],A[0][2j+1]) vs u32[j*512] packing (A[2j][0],A[2j][1]) —
    // the second halves are unrelated entries, so 32 simultaneous bitwise
    // collisions are impossible. Wave-uniform result -> uniform branch.
    const unsigned int* Au = reinterpret_cast<const unsigned int*>(A);
    int votes = 0;
    #pragma unroll
    for (int j = 1; j <= 32; ++j)
        votes += (Au[j] == Au[(size_t)j * 512]) ? 1 : 0;
    const bool is_f32 = (votes >= 31);

    if (is_f32)
        run_can<true>(sh, dx_pi, z0, x0, omega, A, z0b, d_out);
    else
        run_can<false>(sh, dx_pi, z0, x0, omega, A, z0b, d_out);
}

extern "C" void kernel_launch(void* const* d_in, const int* in_sizes, int n_in,
                              void* d_out, int out_size, void* d_ws, size_t ws_size,
                              hipStream_t stream) {
    (void)in_sizes; (void)n_in; (void)d_ws; (void)ws_size; (void)out_size;
    hipLaunchKernelGGL(can_kernel, dim3(NB / 2), dim3(512), 0, stream,
                       d_in[0], d_in[1], d_in[2], d_in[3], d_in[4], d_in[5],
                       d_out);
}

// Round 5
// 1376.261 us; speedup vs baseline: 1.5082x; 1.5082x over previous
//
#include <hip/hip_runtime.h>

// CANPathIntegrator — MI355X round 5 (R4 + step-(3) LDS indexing fix).
// Pure f32 (f16-A chaos-amplifies: R3). NBATCH=4 batches/block -> 128
// blocks -> A L2 traffic halved vs R2, balanced against the f32 FMA floor.
// Per step: zx = T(omega@x) z0hat (owners) -> w = A zx (col-coalesced via
// A symmetry, float4 loads, 4-batch reuse) -> g_k = w[2k+1]zx[2k]-w[2k]zx[2k+1]
// -> dx_can = 0.1 * sum_k g_k omega_k -> rotate carry z, clip x, store.
// R4 bug: reduction step used cg=tid&255 into a [4][128] float4 array ->
// overlapping racy writes + OOB. Now float2 granularity, b=tid>>8, cp=tid&255,
// cols 2cp..2cp+1 of wred[float[4][512]] — in bounds, race-free.

namespace {
constexpr int NT = 128;
constexpr int ND = 512;
constexpr int NBATCH = 4;
constexpr int NBLK = 128;       // 512 / NBATCH
}

struct Shm {
    float4 zx[ND];               // [c] -> 4 batches                  8 KB
    float  wpartT[8][NBATCH][ND];// [q][b][c] row-group partials     64 KB
    float  wred[NBATCH][ND];     // [b][c] reduced w                  8 KB
    float  red[16][NBATCH][2];   // [wave][b][comp]
    float2 dxs[NBATCH];          // final dx_can sums
    float2 dpi[NBATCH][NT];      // dx_pi preload                     4 KB
    float2 om[ND / 2];           // omega pairs                       2 KB
};

__global__ __launch_bounds__(1024) void can_main(
    const float* __restrict__ dx_pi, const float* __restrict__ z0,
    const float* __restrict__ x0, const float* __restrict__ omega,
    const float* __restrict__ A, const float* __restrict__ z0b,
    float* __restrict__ d_out)
{
    __shared__ Shm sh;
    const int tid = threadIdx.x;
    const int b0  = NBATCH * blockIdx.x;

    float* z_seq = d_out;
    float* x_seq = d_out + (size_t)512 * NT * ND;

    // ---- preload dx_pi (4 batches) and omega ----
    if (tid < NBATCH * NT) {                 // 512 threads
        int bb = tid >> 7, tt = tid & 127;
        sh.dpi[bb][tt] =
            reinterpret_cast<const float2*>(dx_pi)[(size_t)(b0 + bb) * NT + tt];
    }
    if (tid < 256)
        sh.om[tid] = reinterpret_cast<const float2*>(omega)[tid];

    // ---- ||z0_base|| ----
    float sq = 0.f;
    if (tid < ND) { float f = z0b[tid]; sq = f * f; }
    #pragma unroll
    for (int o = 1; o < 64; o <<= 1) sq += __shfl_xor(sq, o, 64);
    if ((tid & 63) == 0) sh.red[tid >> 6][0][0] = sq;
    __syncthreads();
    float nsq = 0.f;
    #pragma unroll
    for (int w = 0; w < 16; ++w) nsq += sh.red[w][0][0];
    const float zinv = 1.0f / (sqrtf(nsq) + 1e-5f);

    // ---- owner state: tid<256 owns pair k=tid for all 4 batches ----
    float om0 = 0.f, om1 = 0.f, v0 = 0.f, v1 = 0.f;
    float zr[NBATCH][2] = {}, xr[NBATCH][2] = {};
    if (tid < 256) {
        float2 o2 = sh.om[tid];              // own write, no race
        om0 = o2.x; om1 = o2.y;
        float2 vv = reinterpret_cast<const float2*>(z0b)[tid];
        v0 = vv.x * zinv; v1 = vv.y * zinv;
        #pragma unroll
        for (int b = 0; b < NBATCH; ++b) {
            float2 z2 = reinterpret_cast<const float2*>(z0)[(size_t)(b0 + b) * 256 + tid];
            zr[b][0] = z2.x; zr[b][1] = z2.y;
            float2 x2 = reinterpret_cast<const float2*>(x0)[b0 + b];
            xr[b][0] = x2.x; xr[b][1] = x2.y;
        }
    }

    const int q = tid >> 7;      // row group: rows 64q..64q+63
    const int p = tid & 127;     // col group: cols 4p..4p+3
    const float4* A4 = reinterpret_cast<const float4*>(A);
    const size_t abase = (size_t)(64 * q) * 128 + p;

    for (int t = 0; t < NT; ++t) {
        // (1) zx = T(omega@x) z0hat -> LDS (float4 over batches)
        if (tid < 256) {
            float c0[NBATCH], c1[NBATCH];
            #pragma unroll
            for (int b = 0; b < NBATCH; ++b) {
                float th = om0 * xr[b][0] + om1 * xr[b][1];
                float s, c;
                __sincosf(th, &s, &c);
                c0[b] = c * v0 - s * v1;
                c1[b] = s * v0 + c * v1;
            }
            sh.zx[2 * tid]     = make_float4(c0[0], c0[1], c0[2], c0[3]);
            sh.zx[2 * tid + 1] = make_float4(c1[0], c1[1], c1[2], c1[3]);
        }
        __syncthreads();

        // (2) matvec partials: cols 4p..4p+3 x rows 64q..64q+63 x 4 batches
        float4 acc0 = {0, 0, 0, 0}, acc1 = {0, 0, 0, 0};
        float4 acc2 = {0, 0, 0, 0}, acc3 = {0, 0, 0, 0};
        #pragma unroll 8
        for (int jj = 0; jj < 64; ++jj) {
            float4 a = A4[abase + (size_t)jj * 128];
            float4 z = sh.zx[64 * q + jj];   // broadcast within wave
            acc0.x = fmaf(a.x, z.x, acc0.x);
            acc0.y = fmaf(a.x, z.y, acc0.y);
            acc0.z = fmaf(a.x, z.z, acc0.z);
            acc0.w = fmaf(a.x, z.w, acc0.w);
            acc1.x = fmaf(a.y, z.x, acc1.x);
            acc1.y = fmaf(a.y, z.y, acc1.y);
            acc1.z = fmaf(a.y, z.z, acc1.z);
            acc1.w = fmaf(a.y, z.w, acc1.w);
            acc2.x = fmaf(a.z, z.x, acc2.x);
            acc2.y = fmaf(a.z, z.y, acc2.y);
            acc2.z = fmaf(a.z, z.z, acc2.z);
            acc2.w = fmaf(a.z, z.w, acc2.w);
            acc3.x = fmaf(a.w, z.x, acc3.x);
            acc3.y = fmaf(a.w, z.y, acc3.y);
            acc3.z = fmaf(a.w, z.z, acc3.z);
            acc3.w = fmaf(a.w, z.w, acc3.w);
        }
        // transposed store: per batch, 4 consecutive cols -> one float4
        *reinterpret_cast<float4*>(&sh.wpartT[q][0][4 * p]) =
            make_float4(acc0.x, acc1.x, acc2.x, acc3.x);
        *reinterpret_cast<float4*>(&sh.wpartT[q][1][4 * p]) =
            make_float4(acc0.y, acc1.y, acc2.y, acc3.y);
        *reinterpret_cast<float4*>(&sh.wpartT[q][2][4 * p]) =
            make_float4(acc0.z, acc1.z, acc2.z, acc3.z);
        *reinterpret_cast<float4*>(&sh.wpartT[q][3][4 * p]) =
            make_float4(acc0.w, acc1.w, acc2.w, acc3.w);
        __syncthreads();

        // (3) reduce 8 row-groups at float2 granularity:
        //     thread (b=tid>>8, cp=tid&255) -> wred[b][2cp..2cp+1]
        {
            int b = tid >> 8, cp = tid & 255;
            float sx = 0.f, sy = 0.f;
            #pragma unroll
            for (int qq = 0; qq < 8; ++qq) {
                float2 v = *reinterpret_cast<const float2*>(&sh.wpartT[qq][b][2 * cp]);
                sx += v.x; sy += v.y;
            }
            *reinterpret_cast<float2*>(&sh.wred[b][2 * cp]) = make_float2(sx, sy);
        }
        __syncthreads();

        // (4) g_k * omega_k partials: thread (k=tid>>2, b=tid&3)
        float d0, d1;
        {
            int b = tid & 3, k = tid >> 2;
            float2 wv = reinterpret_cast<const float2*>(sh.wred)[b * 256 + k];
            const float* zxf = reinterpret_cast<const float*>(sh.zx);
            float zc0 = zxf[8 * k + b];              // zx[2k][b]
            float zc1 = zxf[8 * k + 4 + b];          // zx[2k+1][b]
            float g = wv.y * zc0 - wv.x * zc1;
            float2 omk = sh.om[k];
            d0 = g * omk.x;
            d1 = g * omk.y;
        }
        #pragma unroll
        for (int o = 4; o < 64; o <<= 1) {           // keep b = lane&3 separate
            d0 += __shfl_xor(d0, o, 64);
            d1 += __shfl_xor(d1, o, 64);
        }
        if ((tid & 63) < 4) {
            sh.red[tid >> 6][tid & 3][0] = d0;
            sh.red[tid >> 6][tid & 3][1] = d1;
        }
        __syncthreads();

        // (4.5) fold 16 wave-partials -> dxs[b]
        if (tid < 8) {
            int b = tid >> 1, c = tid & 1;
            float s = 0.f;
            #pragma unroll
            for (int w = 0; w < 16; ++w) s += sh.red[w][b][c];
            reinterpret_cast<float*>(&sh.dxs[b])[c] = s;
        }
        __syncthreads();

        // (5) finalize dx_total, rotate carry z, store, clip x
        if (tid < 256) {
            #pragma unroll
            for (int b = 0; b < NBATCH; ++b) {
                float2 ds = sh.dxs[b];
                float2 pi = sh.dpi[b][t];
                float dt0 = pi.x + 0.1f * ds.x;
                float dt1 = pi.y + 0.1f * ds.y;
                float th = om0 * dt0 + om1 * dt1;
                float s, c;
                __sincosf(th, &s, &c);
                float n0 = c * zr[b][0] - s * zr[b][1];
                float n1 = s * zr[b][0] + c * zr[b][1];
                zr[b][0] = n0; zr[b][1] = n1;
                reinterpret_cast<float2*>(z_seq)
                    [((size_t)(b0 + b) * NT + t) * 256 + tid] = make_float2(n0, n1);
                xr[b][0] = fminf(fmaxf(xr[b][0] + dt0, 0.f), 2.0f);
                xr[b][1] = fminf(fmaxf(xr[b][1] + dt1, 0.f), 2.0f);
            }
            if (tid == 0) {
                #pragma unroll
                for (int b = 0; b < NBATCH; ++b)
                    reinterpret_cast<float2*>(x_seq)[(size_t)(b0 + b) * NT + t] =
                        make_float2(xr[b][0], xr[b][1]);
            }
        }
        __syncthreads();
    }
}

extern "C" void kernel_launch(void* const* d_in, const int* in_sizes, int n_in,
                              void* d_out, int out_size, void* d_ws, size_t ws_size,
                              hipStream_t stream) {
    (void)in_sizes; (void)n_in; (void)out_size; (void)d_ws; (void)ws_size;
    hipLaunchKernelGGL(can_main, dim3(NBLK), dim3(1024), 0, stream,
                       (const float*)d_in[0], (const float*)d_in[1],
                       (const float*)d_in[2], (const float*)d_in[3],
                       (const float*)d_in[4], (const float*)d_in[5],
                       (float*)d_out);
}